// Round 2
// baseline (654.701 us; speedup 1.0000x reference)
//
#include <hip/hip_runtime.h>
#include <stdint.h>

#define BATCH 256
#define IN_F  1024
#define OUT_F 1024
#define RT    16      // row tiles (IN_F/64)
#define STN   16      // input bit-streams
#define NCOL  16384   // OUT_F * 8 slices * 2 signs

typedef int v4i  __attribute__((ext_vector_type(4)));
typedef int v16i __attribute__((ext_vector_type(16)));

// ---------------------------------------------------------------------------
// A_packed[t][b][k] : one byte = bit t of the 16-bit two's-complement
// quantized x[b][k].  4 MB.
// ---------------------------------------------------------------------------
__global__ __launch_bounds__(256) void pack_A(const float* __restrict__ x,
                                              uint8_t* __restrict__ Ap) {
    int item = blockIdx.x * 256 + threadIdx.x;      // 262144 items
    int ks = item & 63;          // 16-byte k-slot within the 1024 k's
    int t  = (item >> 6) & 15;
    int b  = item >> 10;
    const float* xr = x + (size_t)b * IN_F + ks * 16;
    uint32_t dw[4];
    #pragma unroll
    for (int q = 0; q < 4; ++q) {
        uint32_t d = 0;
        #pragma unroll
        for (int j = 0; j < 4; ++j) {
            float xf = rintf(xr[q * 4 + j] * 4096.0f);
            xf = fminf(fmaxf(xf, -32768.0f), 32767.0f);
            int xi = (int)xf;
            uint32_t xu = (uint32_t)xi & 0xFFFFu;   // two's complement low 16
            d |= ((xu >> t) & 1u) << (8 * j);
        }
        dw[q] = d;
    }
    *(uint4*)(Ap + ((size_t)(t * BATCH + b) * IN_F + ks * 16)) =
        make_uint4(dw[0], dw[1], dw[2], dw[3]);
}

// ---------------------------------------------------------------------------
// B_packed[g][c][16] : for k-slot g (k = g*16+j), column c = o*16 + sg*8 + s,
// byte j = 2-bit slice s of sign-part sg of w[o][k].  16.7 MB.
// Layout matches the MFMA B-fragment load: lane reads 16 contiguous k-bytes
// at its column.
// ---------------------------------------------------------------------------
__global__ __launch_bounds__(256) void pack_B(const float* __restrict__ w,
                                              uint8_t* __restrict__ Bp) {
    int item = blockIdx.x * 256 + threadIdx.x;      // 1048576 items
    int c = item & (NCOL - 1);
    int g = item >> 14;          // 0..63
    int o  = c >> 4;
    int sg = (c >> 3) & 1;
    int s  = c & 7;
    int sh = 14 - 2 * s;
    const float* wr = w + (size_t)o * IN_F + g * 16;
    uint32_t dw[4];
    #pragma unroll
    for (int q = 0; q < 4; ++q) {
        uint32_t d = 0;
        #pragma unroll
        for (int j = 0; j < 4; ++j) {
            float wv = wr[q * 4 + j];
            float wf = rintf(fmaxf(sg ? -wv : wv, 0.0f) * 4096.0f);
            wf = fminf(wf, 65535.0f);
            uint32_t wi = (uint32_t)wf;
            d |= ((wi >> sh) & 3u) << (8 * j);
        }
        dw[q] = d;
    }
    *(uint4*)(Bp + (size_t)(g * NCOL + c) * 16) =
        make_uint4(dw[0], dw[1], dw[2], dw[3]);
}

// ---------------------------------------------------------------------------
// Main: wave = 32b x 32col C-tile.  col = o*16 + sg*8 + s -> sign & slice
// weight folded into per-lane constant; t-stream weight folded per iteration.
// A(r, all 16 t) staged to LDS once per r via global_load_lds (source
// XOR-swizzled so frag ds_read_b128 is only 4-way bank conflicted).
// ADC identical bits to previous passing kernel: qf = rintf(a * 85/64) with
// exact fp32 product; contribution qf * (±step*4^(7-s)*2^t), all-exact
// scale factors.
// ---------------------------------------------------------------------------
__global__ __launch_bounds__(256, 4) void cim_mfma(
    const uint8_t* __restrict__ Ap, const uint8_t* __restrict__ Bp,
    const float* __restrict__ bias, float* __restrict__ out)
{
    __shared__ __align__(16) uint8_t Abuf[STN * 2048];   // 32 KB
    int tid = threadIdx.x, wid = tid >> 6, l = tid & 63;
    int cb = blockIdx.x;                 // 128-column block index (0..127)
    int b0 = blockIdx.y * 32;
    int col = cb * 128 + wid * 32 + (l & 31);
    int s  = col & 7;
    int sg = (col >> 3) & 1;
    float clane = ldexpf(192.0f / 255.0f, 14 - 2 * s);   // step * 4^(7-s)
    if (sg) clane = -clane;

    float acc[16];
    #pragma unroll
    for (int i = 0; i < 16; ++i) acc[i] = 0.0f;
    v16i zero;
    #pragma unroll
    for (int i = 0; i < 16; ++i) zero[i] = 0;

    const int row_f = l & 31;                 // fragment row (b offset)
    const int swz_f = (row_f >> 1) & 3;
    const int h2    = l >> 5;                 // k-granule half
    const int srow0 = l >> 2;                 // staging row within 16
    const int sslot = l & 3;                  // staging 16B slot

    for (int r = 0; r < RT; ++r) {
        // B fragments for this r, held across the t loop (K = r*64 .. +64)
        const uint8_t* bp0 = Bp + ((size_t)(r * 4 + 0 + h2) * NCOL + col) * 16;
        const uint8_t* bp1 = Bp + ((size_t)(r * 4 + 2 + h2) * NCOL + col) * 16;
        v4i bf0 = *(const v4i*)bp0;
        v4i bf1 = *(const v4i*)bp1;

        __syncthreads();   // previous iteration's frag reads done
        #pragma unroll
        for (int tt = 0; tt < 4; ++tt) {
            int t = wid * 4 + tt;
            #pragma unroll
            for (int hh = 0; hh < 2; ++hh) {
                int row  = hh * 16 + srow0;
                int slot = sslot ^ ((row >> 1) & 3);   // pre-swizzled source
                const uint8_t* src = Ap + (size_t)(t * BATCH + b0 + row) * IN_F
                                        + r * 64 + slot * 16;
                __builtin_amdgcn_global_load_lds(
                    (const __attribute__((address_space(1))) uint32_t*)src,
                    (__attribute__((address_space(3))) uint32_t*)(Abuf + t * 2048 + hh * 1024),
                    16, 0, 0);
            }
        }
        __syncthreads();   // staging landed (compiler drains vmcnt)

        #pragma unroll
        for (int t = 0; t < STN; ++t) {
            int sl0 = (0 + h2) ^ swz_f;
            int sl1 = (2 + h2) ^ swz_f;
            v4i af0 = *(const v4i*)(Abuf + t * 2048 + row_f * 64 + sl0 * 16);
            v4i af1 = *(const v4i*)(Abuf + t * 2048 + row_f * 64 + sl1 * 16);
            v16i c = __builtin_amdgcn_mfma_i32_32x32x32_i8(af0, bf0, zero, 0, 0, 0);
            c      = __builtin_amdgcn_mfma_i32_32x32x32_i8(af1, bf1, c,    0, 0, 0);
            const float wt = (t == 15) ? -32768.0f : (float)(1 << t);
            float cw = clane * wt;                    // exact power-of-2 scale
            #pragma unroll
            for (int i = 0; i < 16; ++i) {
                float af = (float)c[i];               // v_cvt_f32_i32
                float qf = rintf(af * 1.328125f);     // round(a*85/64), half-even
                acc[i] = fmaf(qf, cw, acc[i]);
            }
        }
    }

    // reduce the 16 (sg,s) columns of each output across the 16-lane group
    #pragma unroll
    for (int st = 1; st < 16; st <<= 1) {
        #pragma unroll
        for (int i = 0; i < 16; ++i)
            acc[i] += __shfl_xor(acc[i], st, 64);
    }
    int m = l & 15;
    int g = (l >> 4) & 1;
    float ov = acc[0];
    #pragma unroll
    for (int i = 1; i < 16; ++i) ov = (m == i) ? acc[i] : ov;  // static-index select
    int orow = (m & 3) + 8 * (m >> 2) + 4 * h2;   // C/D row mapping (32x32)
    int o = cb * 8 + wid * 2 + g;
    float ovs = ov * 0x1p-24f;
    float q = rintf(ovs * 4096.0f);
    q = fminf(fmaxf(q, -32768.0f), 32767.0f);
    out[(size_t)(b0 + orow) * OUT_F + o] = q * 0x1p-12f + bias[o];
}

// ---------------------------------------------------------------------------
extern "C" void kernel_launch(void* const* d_in, const int* in_sizes, int n_in,
                              void* d_out, int out_size, void* d_ws, size_t ws_size,
                              hipStream_t stream) {
    const float* x    = (const float*)d_in[0];
    const float* w    = (const float*)d_in[1];
    const float* bias = (const float*)d_in[2];
    float* out = (float*)d_out;

    uint8_t* Ap = (uint8_t*)d_ws;                              // 4 MB
    uint8_t* Bp = Ap + (size_t)STN * BATCH * IN_F;             // 16.7 MB

    hipLaunchKernelGGL(pack_A, dim3(1024), dim3(256), 0, stream, x, Ap);
    hipLaunchKernelGGL(pack_B, dim3(4096), dim3(256), 0, stream, w, Bp);
    hipLaunchKernelGGL(cim_mfma, dim3(128, 8), dim3(256), 0, stream,
                       Ap, Bp, bias, out);
}

// Round 3
// 224.792 us; speedup vs baseline: 2.9125x; 2.9125x over previous
//
#include <hip/hip_runtime.h>
#include <stdint.h>

#define BATCH 256
#define IN_F  1024
#define OUT_F 1024
#define RT    16      // row tiles (IN_F/64)
#define STN   16      // input bit-streams
#define NCOL  16384   // 16 (sg,s) groups * 1024 outputs

typedef int v4i  __attribute__((ext_vector_type(4)));
typedef int v16i __attribute__((ext_vector_type(16)));

// ---------------------------------------------------------------------------
// ws layout: Ap 4MB | Bp 16MB | Part 16MB | flags 512B
// ---------------------------------------------------------------------------
#define AP_SZ   ((size_t)STN * BATCH * IN_F)
#define BP_SZ   ((size_t)64 * NCOL * 16)
#define PART_SZ ((size_t)16 * BATCH * OUT_F * sizeof(float))

// ---------------------------------------------------------------------------
// A_packed[t][b][k] : byte = bit t of 16-bit two's-complement quantized x.
// Also zero-inits the 128-word flag array (block 0 only; flags are consumed
// by the NEXT dispatch, so no race).
// ---------------------------------------------------------------------------
__global__ __launch_bounds__(256) void pack_A(const float* __restrict__ x,
                                              uint8_t* __restrict__ Ap,
                                              uint32_t* __restrict__ flags) {
    if (blockIdx.x == 0 && threadIdx.x < 128) flags[threadIdx.x] = 0;
    int item = blockIdx.x * 256 + threadIdx.x;      // 262144 items
    int ks = item & 63;
    int t  = (item >> 6) & 15;
    int b  = item >> 10;
    const float* xr = x + (size_t)b * IN_F + ks * 16;
    uint32_t dw[4];
    #pragma unroll
    for (int q = 0; q < 4; ++q) {
        uint32_t d = 0;
        #pragma unroll
        for (int j = 0; j < 4; ++j) {
            float xf = rintf(xr[q * 4 + j] * 4096.0f);
            xf = fminf(fmaxf(xf, -32768.0f), 32767.0f);
            int xi = (int)xf;
            uint32_t xu = (uint32_t)xi & 0xFFFFu;
            d |= ((xu >> t) & 1u) << (8 * j);
        }
        dw[q] = d;
    }
    *(uint4*)(Ap + ((size_t)(t * BATCH + b) * IN_F + ks * 16)) =
        make_uint4(dw[0], dw[1], dw[2], dw[3]);
}

// ---------------------------------------------------------------------------
// B_packed[g][c][16], c = (sg*8+s)*1024 + o.  byte j = 2-bit slice s of
// sign-part sg of w[o][g*16+j].  Sets flags[cb] bit r if the (128-o x 64-k)
// tile has any nonzero slice byte (cb = c>>7, r = g>>2; both wave-uniform
// because a wave spans 64 consecutive c within a 64-aligned range).
// ---------------------------------------------------------------------------
__global__ __launch_bounds__(256) void pack_B(const float* __restrict__ w,
                                              uint8_t* __restrict__ Bp,
                                              uint32_t* __restrict__ flags) {
    int item = blockIdx.x * 256 + threadIdx.x;      // 1048576 items
    int c = item & (NCOL - 1);
    int g = item >> 14;          // 0..63
    int o   = c & 1023;
    int sgs = c >> 10;
    int s  = sgs & 7;
    int sg = sgs >> 3;
    int sh = 14 - 2 * s;
    const float* wr = w + (size_t)o * IN_F + g * 16;
    uint32_t dw[4], nz = 0;
    #pragma unroll
    for (int q = 0; q < 4; ++q) {
        uint32_t d = 0;
        #pragma unroll
        for (int j = 0; j < 4; ++j) {
            float wv = wr[q * 4 + j];
            float wf = rintf(fmaxf(sg ? -wv : wv, 0.0f) * 4096.0f);
            wf = fminf(wf, 65535.0f);
            uint32_t wi = (uint32_t)wf;
            d |= ((wi >> sh) & 3u) << (8 * j);
        }
        dw[q] = d;
        nz |= d;
    }
    *(uint4*)(Bp + (size_t)(g * NCOL + c) * 16) =
        make_uint4(dw[0], dw[1], dw[2], dw[3]);
    int any = __any((int)(nz != 0));
    if ((threadIdx.x & 63) == 0 && any)
        atomicOr(&flags[c >> 7], 1u << (g >> 2));
}

// ---------------------------------------------------------------------------
// Main: block = 32 b x 128 col, all 4 waves share one (sg,s) group.
// Per-(cb,r) flag skips B-load + A-staging + MFMA + epilogue when the B tile
// is all-zero (exact: c==0 -> ADC(0)==0 -> contribution 0).
// ADC bits identical to the verified R1/R2 formula.  Partials to ws;
// reduce_out does the cross-(sg,s) sum + ACM quantize + bias.
// ---------------------------------------------------------------------------
__global__ __launch_bounds__(256, 2) void cim_mfma(
    const uint8_t* __restrict__ Ap, const uint8_t* __restrict__ Bp,
    const uint32_t* __restrict__ flags, float* __restrict__ part)
{
    __shared__ __align__(16) uint8_t Abuf[STN * 2048];   // 32 KB
    int tid = threadIdx.x, wid = tid >> 6, l = tid & 63;
    int cb = blockIdx.x;                 // 0..127
    int b0 = blockIdx.y * 32;
    int sgs = cb >> 3;
    int s  = sgs & 7;
    int sg = sgs >> 3;
    int col = cb * 128 + wid * 32 + (l & 31);
    float clane = ldexpf(192.0f / 255.0f, 14 - 2 * s);   // step * 4^(7-s), exact scale
    if (sg) clane = -clane;
    uint32_t fb = flags[cb];

    float acc[16];
    #pragma unroll
    for (int i = 0; i < 16; ++i) acc[i] = 0.0f;
    v16i zero;
    #pragma unroll
    for (int i = 0; i < 16; ++i) zero[i] = 0;

    const int row_f = l & 31;
    const int swz_f = (row_f >> 1) & 3;
    const int h2    = l >> 5;
    const int srow0 = l >> 2;
    const int sslot = l & 3;

    for (int r = 0; r < RT; ++r) {
        if (!((fb >> r) & 1u)) continue;        // uniform: whole block skips

        v4i bf0 = *(const v4i*)(Bp + ((size_t)(r * 4 + 0 + h2) * NCOL + col) * 16);
        v4i bf1 = *(const v4i*)(Bp + ((size_t)(r * 4 + 2 + h2) * NCOL + col) * 16);

        __syncthreads();   // previous r's frag reads done before overwrite
        #pragma unroll
        for (int tt = 0; tt < 4; ++tt) {
            int t = wid * 4 + tt;
            #pragma unroll
            for (int hh = 0; hh < 2; ++hh) {
                int row  = hh * 16 + srow0;
                int slot = sslot ^ ((row >> 1) & 3);   // pre-swizzled source
                const uint8_t* src = Ap + (size_t)(t * BATCH + b0 + row) * IN_F
                                        + r * 64 + slot * 16;
                __builtin_amdgcn_global_load_lds(
                    (const __attribute__((address_space(1))) uint32_t*)src,
                    (__attribute__((address_space(3))) uint32_t*)(Abuf + t * 2048 + hh * 1024),
                    16, 0, 0);
            }
        }
        __syncthreads();   // staging landed (vmcnt drained at barrier)

        #pragma unroll 4
        for (int t = 0; t < STN; ++t) {
            int sl0 = h2 ^ swz_f;
            int sl1 = (2 + h2) ^ swz_f;
            v4i af0 = *(const v4i*)(Abuf + t * 2048 + row_f * 64 + sl0 * 16);
            v4i af1 = *(const v4i*)(Abuf + t * 2048 + row_f * 64 + sl1 * 16);
            v16i c = __builtin_amdgcn_mfma_i32_32x32x32_i8(af0, bf0, zero, 0, 0, 0);
            c      = __builtin_amdgcn_mfma_i32_32x32x32_i8(af1, bf1, c,    0, 0, 0);
            float wt = (t == 15) ? -32768.0f : (float)(1 << t);
            float cw = clane * wt;                    // exact power-of-2 scale
            #pragma unroll
            for (int i = 0; i < 16; ++i) {
                float af = (float)c[i];               // v_cvt_f32_i32
                float qf = rintf(af * 1.328125f);     // round(a*85/64), half-even
                acc[i] = fmaf(qf, cw, acc[i]);
            }
        }
    }

    // unconditional partial write (zeros for fully-skipped blocks)
    int o = (cb & 7) * 128 + wid * 32 + (l & 31);
    #pragma unroll
    for (int i = 0; i < 16; ++i) {
        int b = b0 + (i & 3) + 8 * (i >> 2) + 4 * h2;  // 32x32 C/D row map
        part[((size_t)sgs * BATCH + b) * OUT_F + o] = acc[i];
    }
}

// ---------------------------------------------------------------------------
__global__ __launch_bounds__(256) void reduce_out(
    const float* __restrict__ part, const float* __restrict__ bias,
    float* __restrict__ out)
{
    int idx = blockIdx.x * 256 + threadIdx.x;
    int o = idx & (OUT_F - 1), b = idx >> 10;
    float ov = 0.0f;
    #pragma unroll
    for (int sgs = 0; sgs < 16; ++sgs)
        ov += part[((size_t)sgs * BATCH + b) * OUT_F + o];
    ov *= 0x1p-24f;
    float q = rintf(ov * 4096.0f);
    q = fminf(fmaxf(q, -32768.0f), 32767.0f);
    out[idx] = q * 0x1p-12f + bias[o];
}

// ---------------------------------------------------------------------------
extern "C" void kernel_launch(void* const* d_in, const int* in_sizes, int n_in,
                              void* d_out, int out_size, void* d_ws, size_t ws_size,
                              hipStream_t stream) {
    const float* x    = (const float*)d_in[0];
    const float* w    = (const float*)d_in[1];
    const float* bias = (const float*)d_in[2];
    float* out = (float*)d_out;

    uint8_t*  Ap    = (uint8_t*)d_ws;
    uint8_t*  Bp    = Ap + AP_SZ;
    float*    Part  = (float*)(Bp + BP_SZ);
    uint32_t* flags = (uint32_t*)((uint8_t*)Part + PART_SZ);

    hipLaunchKernelGGL(pack_A, dim3(1024), dim3(256), 0, stream, x, Ap, flags);
    hipLaunchKernelGGL(pack_B, dim3(4096), dim3(256), 0, stream, w, Bp, flags);
    hipLaunchKernelGGL(cim_mfma, dim3(128, 8), dim3(256), 0, stream,
                       Ap, Bp, flags, Part);
    hipLaunchKernelGGL(reduce_out, dim3(BATCH * OUT_F / 256), dim3(256), 0, stream,
                       Part, bias, out);
}